// Round 1
// baseline (143.007 us; speedup 1.0000x reference)
//
#include <hip/hip_runtime.h>

// Word2Vec negative-sampling scores: out[b][c] = dot(embed[targets[b]], embed[contexts[b][c]])
// B=16384, NCTX=6, E=128, fp32.
//
// Mapping: one 64-lane wave handles TWO batch elements (one per 32-lane half).
//   - half = lane>>5 selects b = wave*2 + half; sl = lane&31
//   - sl reads float4 = row elements [4*sl .. 4*sl+3]  (32 lanes x 16 B = 512 B row;
//     one load instruction covers 2 rows = 1 KB)
//   - all 6 context-row loads issued up front (~7 KB in flight per wave)
//   - 5-step shfl_xor butterfly within each 32-lane half leaves ALL lanes holding
//     all 6 sums -> lanes 0..5 of each half store p[sl]: ONE 48-B-contiguous
//     store instruction per wave instead of 6 scalar stores per half.
//
// __launch_bounds__(256, 8): force 8 waves/EU (VGPR <= 64). The kernel is a
// one-burst random gather; throughput ~ waves/SIMD x loads/wave in flight.
// Live set is ~50 VGPR so this fits without spills; without the bound the
// allocator may drift past 64 and silently halve occupancy.

constexpr int EMBED = 128;
constexpr int NCTX  = 6;

__global__ __launch_bounds__(256, 8) void Word2VecNS_kernel(
    const int*   __restrict__ targets,
    const int*   __restrict__ contexts,
    const float* __restrict__ embed,
    float*       __restrict__ out,
    int batch)
{
    const int wave = (blockIdx.x * blockDim.x + threadIdx.x) >> 6;
    const int lane = threadIdx.x & 63;
    const int half = lane >> 5;          // 0 or 1: which batch element this lane serves
    const int sl   = lane & 31;          // sub-lane within the half
    const int b    = wave * 2 + half;
    if (b >= batch) return;              // batch is even; full waves in practice

    // Context indices first (independent of targets load -> overlap latency):
    // 6 ints = 24 B at offset b*24 (8B-aligned) -> 3 x int2
    int cidx[NCTX];
    {
        const int2* cp = (const int2*)(contexts + (size_t)b * NCTX);
        int2 c01 = cp[0], c23 = cp[1], c45 = cp[2];
        cidx[0] = c01.x; cidx[1] = c01.y;
        cidx[2] = c23.x; cidx[3] = c23.y;
        cidx[4] = c45.x; cidx[5] = c45.y;
    }
    const int t = targets[b];

    // Row gathers: float4 per lane (16 B x 32 lanes = 512 B row). Issue target
    // row then all 6 context rows before any use (latency overlap).
    const float4* erow = (const float4*)embed;     // row r = erow[r*32 + sl]
    const float4 tv = erow[(size_t)t * (EMBED / 4) + sl];

    float4 cv[NCTX];
#pragma unroll
    for (int c = 0; c < NCTX; ++c)
        cv[c] = erow[(size_t)cidx[c] * (EMBED / 4) + sl];

    // Per-lane partial dots
    float p[NCTX];
#pragma unroll
    for (int c = 0; c < NCTX; ++c)
        p[c] = tv.x * cv[c].x + tv.y * cv[c].y + tv.z * cv[c].z + tv.w * cv[c].w;

    // Butterfly reduction within each 32-lane half (xor offsets < 32 never cross halves).
    // Afterwards every lane of the half holds the full sums for all 6 contexts.
#pragma unroll
    for (int off = 16; off > 0; off >>= 1) {
#pragma unroll
        for (int c = 0; c < NCTX; ++c)
            p[c] += __shfl_xor(p[c], off, 64);
    }

    // Coalesced epilogue: lanes 0..5 of each half write p[sl].
    // Active lanes {0..5, 32..37} cover out[wave*12 .. wave*12+11] = 48
    // contiguous bytes -> a single global_store_dword per wave.
    if (sl < NCTX) {
        float v = p[0];
#pragma unroll
        for (int c = 1; c < NCTX; ++c)
            v = (sl == c) ? p[c] : v;    // branchless cndmask chain
        out[(size_t)b * NCTX + sl] = v;
    }
}

extern "C" void kernel_launch(void* const* d_in, const int* in_sizes, int n_in,
                              void* d_out, int out_size, void* d_ws, size_t ws_size,
                              hipStream_t stream) {
    const int*   targets  = (const int*)d_in[0];
    const int*   contexts = (const int*)d_in[1];
    const float* embed    = (const float*)d_in[2];
    float*       out      = (float*)d_out;

    const int batch = in_sizes[0];                     // 16384
    const int elems_per_block = (256 / 64) * 2;        // 4 waves x 2 elements = 8
    const int blocks = (batch + elems_per_block - 1) / elems_per_block;

    Word2VecNS_kernel<<<blocks, 256, 0, stream>>>(targets, contexts, embed, out, batch);
}